// Round 1
// baseline (1023.331 us; speedup 1.0000x reference)
//
#include <hip/hip_runtime.h>
#include <hip/hip_bf16.h>
#include <float.h>

#define D 128
#define NGRAPHS 64

// ---- ordered-float encoding for atomicMax on unsigned ----
__device__ __forceinline__ unsigned fkey(float f){
  unsigned u = __float_as_uint(f);
  return (u & 0x80000000u) ? ~u : (u | 0x80000000u);
}
__device__ __forceinline__ float funkey(unsigned k){
  unsigned u = (k & 0x80000000u) ? (k ^ 0x80000000u) : ~k;
  return __uint_as_float(u);
}

// 1) histogram of dst (deg = cnt + 1 for self-loop)
__global__ void k_hist(const int* __restrict__ dst, int* __restrict__ cnt, int E){
  int e = blockIdx.x * blockDim.x + threadIdx.x;
  if (e < E) atomicAdd(&cnt[dst[e]], 1);
}

// 2) single-block exclusive scan over cnt -> row_ptr[N+1], cursor[N]
__global__ __launch_bounds__(1024) void k_scan(const int* __restrict__ cnt,
                       int* __restrict__ row_ptr, int* __restrict__ cursor,
                       int N, int E){
  __shared__ int sh[1024];
  __shared__ int carry;
  int tid = threadIdx.x;
  if (tid == 0) carry = 0;
  __syncthreads();
  for (int base = 0; base < N; base += 1024){
    int v = (base + tid < N) ? cnt[base + tid] : 0;
    sh[tid] = v;
    __syncthreads();
    for (int off = 1; off < 1024; off <<= 1){
      int x = (tid >= off) ? sh[tid - off] : 0;
      __syncthreads();
      sh[tid] += x;
      __syncthreads();
    }
    int incl = sh[tid];
    int c = carry;
    if (base + tid < N){
      int excl = c + incl - v;
      row_ptr[base + tid] = excl;
      cursor[base + tid]  = excl;
    }
    int total = sh[1023];
    __syncthreads();
    if (tid == 0) carry = c + total;
    __syncthreads();
  }
  if (tid == 0) row_ptr[N] = E;
}

// 3) scatter edges into CSR (order within a node is arbitrary -> fp32 sum reorder ok)
__global__ void k_fill(const int* __restrict__ src, const int* __restrict__ dst,
                       int* __restrict__ cursor, int* __restrict__ col, int E){
  int e = blockIdx.x * blockDim.x + threadIdx.x;
  if (e < E){
    int pos = atomicAdd(&cursor[dst[e]], 1);
    col[pos] = src[e];
  }
}

// 4) dinv = rsqrt(deg), deg >= 1 always (self-loop)
__global__ void k_dinv(const int* __restrict__ cnt, float* __restrict__ dinv, int N){
  int i = blockIdx.x * blockDim.x + threadIdx.x;
  if (i < N) dinv[i] = rsqrtf((float)cnt[i] + 1.0f);
}

// 5) fp32 GEMM: C[M,128] = A[M,128] @ W[128,128]
//    BM=64, BK=32; block 256 threads; thread = 8 rows x 4 cols micro-tile.
__global__ __launch_bounds__(256) void gemm128(const float* __restrict__ A,
    const float* __restrict__ W, float* __restrict__ C, int M){
  __shared__ float Ws[32 * 128];   // 16 KB, [k][col] linear
  __shared__ float At[32 * 64];    // 8 KB,  [k][row]
  int t = threadIdx.x;
  int rowBase = blockIdx.x * 64;
  int c0 = (t & 31) * 4;
  int r0 = (t >> 5) * 8;
  float acc[8][4] = {};
  for (int k0 = 0; k0 < 128; k0 += 32){
    // W tile: rows k0..k0+31, all cols -> contiguous 4096 floats
    const float* wt = W + k0 * 128;
    #pragma unroll
    for (int j = 0; j < 4; j++){
      int idx = j * 1024 + t * 4;
      *(float4*)&Ws[idx] = *(const float4*)&wt[idx];
    }
    // A tile: 64 rows x 32 k, stored transposed At[k][row]
    #pragma unroll
    for (int j = 0; j < 2; j++){
      int lid = t + j * 256;        // 0..511
      int row = lid >> 3;
      int kk  = (lid & 7) * 4;
      int gr = rowBase + row; if (gr >= M) gr = M - 1;
      float4 v = *(const float4*)&A[(size_t)gr * D + k0 + kk];
      At[(kk + 0) * 64 + row] = v.x;
      At[(kk + 1) * 64 + row] = v.y;
      At[(kk + 2) * 64 + row] = v.z;
      At[(kk + 3) * 64 + row] = v.w;
    }
    __syncthreads();
    #pragma unroll
    for (int kk = 0; kk < 32; kk++){
      float4 b = *(float4*)&Ws[kk * 128 + c0];
      float4 a0 = *(float4*)&At[kk * 64 + r0];
      float4 a1 = *(float4*)&At[kk * 64 + r0 + 4];
      float av[8] = {a0.x, a0.y, a0.z, a0.w, a1.x, a1.y, a1.z, a1.w};
      #pragma unroll
      for (int r = 0; r < 8; r++){
        acc[r][0] += av[r] * b.x;
        acc[r][1] += av[r] * b.y;
        acc[r][2] += av[r] * b.z;
        acc[r][3] += av[r] * b.w;
      }
    }
    __syncthreads();
  }
  #pragma unroll
  for (int r = 0; r < 8; r++){
    int gr = rowBase + r0 + r;
    if (gr < M) *(float4*)&C[(size_t)gr * D + c0] = *(float4*)&acc[r][0];
  }
}

// 6) CSR aggregation: out[i] = sum_{s in N(i)} t[s]*dinv[s]*dinv[i] + t[i]*dinv[i]^2 + b; opt relu
__global__ __launch_bounds__(128) void k_agg(const float* __restrict__ t,
    const int* __restrict__ row_ptr, const int* __restrict__ col,
    const float* __restrict__ dinv, const float* __restrict__ bias,
    float* __restrict__ out, int relu){
  int i = blockIdx.x;
  int d = threadIdx.x;
  __shared__ int   scol[128];
  __shared__ float sw[128];
  float di = dinv[i];
  float acc = t[(size_t)i * D + d] * di * di + bias[d];   // self-loop + bias
  int beg = row_ptr[i], end = row_ptr[i + 1];
  for (int base = beg; base < end; base += 128){
    int m = end - base; if (m > 128) m = 128;
    if (d < m){ int s = col[base + d]; scol[d] = s; sw[d] = dinv[s] * di; }
    __syncthreads();
    for (int j = 0; j < m; j++)
      acc += t[(size_t)scol[j] * D + d] * sw[j];
    __syncthreads();
  }
  out[(size_t)i * D + d] = relu ? fmaxf(acc, 0.0f) : acc;
}

// 7) chunked segment-max into ordered-uint atomicMax (batch is sorted)
__global__ __launch_bounds__(128) void k_pool(const float* __restrict__ h,
    const int* __restrict__ batch, unsigned* __restrict__ pk, int N){
  int d = threadIdx.x;
  int n0 = blockIdx.x * 128;
  int nEnd = n0 + 128; if (nEnd > N) nEnd = N;
  float cur = -FLT_MAX;
  int curg = batch[n0];
  for (int n = n0; n < nEnd; n++){
    int g = batch[n];
    if (g != curg){
      atomicMax(&pk[curg * D + d], fkey(cur));
      cur = -FLT_MAX; curg = g;
    }
    cur = fmaxf(cur, h[(size_t)n * D + d]);
  }
  atomicMax(&pk[curg * D + d], fkey(cur));
}

// 8) final: out[64,2] = pooled @ Wf + bf
__global__ __launch_bounds__(128) void k_final(const unsigned* __restrict__ pk,
    const float* __restrict__ Wf, const float* __restrict__ bf,
    float* __restrict__ out){
  int t = threadIdx.x;            // 0..127
  int g = t >> 1, c = t & 1;
  float s = bf[c];
  for (int k = 0; k < D; k++)
    s += funkey(pk[g * D + k]) * Wf[k * 2 + c];
  out[g * 2 + c] = s;
}

extern "C" void kernel_launch(void* const* d_in, const int* in_sizes, int n_in,
                              void* d_out, int out_size, void* d_ws, size_t ws_size,
                              hipStream_t stream){
  const float* x   = (const float*)d_in[0];
  const int*   ei  = (const int*)d_in[1];
  const int*   bat = (const int*)d_in[2];
  const float* W0  = (const float*)d_in[3];
  const float* b0  = (const float*)d_in[4];
  const float* W1  = (const float*)d_in[5];
  const float* b1  = (const float*)d_in[6];
  const float* W2  = (const float*)d_in[7];
  const float* b2  = (const float*)d_in[8];
  const float* Wf  = (const float*)d_in[9];
  const float* bf  = (const float*)d_in[10];
  int N = in_sizes[0] / D;
  int E = in_sizes[1] / 2;
  const int* srcp = ei;
  const int* dstp = ei + E;

  char* p = (char*)d_ws;
  auto alloc = [&](size_t bytes)->char*{
    char* r = p; p += (bytes + 255) & ~(size_t)255; return r;
  };
  float*    dinv    = (float*)alloc((size_t)N * 4);
  int*      cnt     = (int*)alloc((size_t)N * 4);
  int*      row_ptr = (int*)alloc((size_t)(N + 1) * 4);
  int*      cursor  = (int*)alloc((size_t)N * 4);
  int*      col     = (int*)alloc((size_t)E * 4);
  float*    tmp     = (float*)alloc((size_t)N * D * 4);
  float*    hbuf    = (float*)alloc((size_t)N * D * 4);
  unsigned* pk      = (unsigned*)alloc((size_t)NGRAPHS * D * 4);

  hipMemsetAsync(cnt, 0, (size_t)N * 4, stream);
  hipMemsetAsync(pk, 0, (size_t)NGRAPHS * D * 4, stream);

  k_hist<<<(E + 255) / 256, 256, 0, stream>>>(dstp, cnt, E);
  k_scan<<<1, 1024, 0, stream>>>(cnt, row_ptr, cursor, N, E);
  k_fill<<<(E + 255) / 256, 256, 0, stream>>>(srcp, dstp, cursor, col, E);
  k_dinv<<<(N + 255) / 256, 256, 0, stream>>>(cnt, dinv, N);

  int gblocks = (N + 63) / 64;
  // layer 0
  gemm128<<<gblocks, 256, 0, stream>>>(x, W0, tmp, N);
  k_agg<<<N, 128, 0, stream>>>(tmp, row_ptr, col, dinv, b0, hbuf, 1);
  // layer 1
  gemm128<<<gblocks, 256, 0, stream>>>(hbuf, W1, tmp, N);
  k_agg<<<N, 128, 0, stream>>>(tmp, row_ptr, col, dinv, b1, hbuf, 1);
  // layer 2 (no relu)
  gemm128<<<gblocks, 256, 0, stream>>>(hbuf, W2, tmp, N);
  k_agg<<<N, 128, 0, stream>>>(tmp, row_ptr, col, dinv, b2, hbuf, 0);
  // pool + classifier
  k_pool<<<(N + 127) / 128, 128, 0, stream>>>(hbuf, bat, pk, N);
  k_final<<<1, 128, 0, stream>>>(pk, Wf, bf, (float*)d_out);
}

// Round 2
// 846.293 us; speedup vs baseline: 1.2092x; 1.2092x over previous
//
#include <hip/hip_runtime.h>
#include <hip/hip_bf16.h>
#include <float.h>

#define D 128
#define NGRAPHS 64
#define SCHUNK 2048   // scan chunk per block (256 threads x 8)

// ---- ordered-float encoding for atomicMax on unsigned ----
__device__ __forceinline__ unsigned fkey(float f){
  unsigned u = __float_as_uint(f);
  return (u & 0x80000000u) ? ~u : (u | 0x80000000u);
}
__device__ __forceinline__ float funkey(unsigned k){
  unsigned u = (k & 0x80000000u) ? (k ^ 0x80000000u) : ~k;
  return __uint_as_float(u);
}

// 1) histogram of dst (deg = cnt + 1 for self-loop)
__global__ void k_hist(const int* __restrict__ dst, int* __restrict__ cnt, int E){
  int e = blockIdx.x * blockDim.x + threadIdx.x;
  if (e < E) atomicAdd(&cnt[dst[e]], 1);
}

// 2a) per-block sums over 2048-elem chunks
__global__ __launch_bounds__(256) void k_scan1(const int* __restrict__ cnt,
    int* __restrict__ blockSums, int N){
  __shared__ int sh[256];
  int t = threadIdx.x;
  int base = blockIdx.x * SCHUNK + t * 8;
  int s = 0;
  if (base + 7 < N){
    int4 a = *(const int4*)&cnt[base];
    int4 b = *(const int4*)&cnt[base + 4];
    s = a.x + a.y + a.z + a.w + b.x + b.y + b.z + b.w;
  } else {
    for (int j = 0; j < 8; j++){ int i = base + j; if (i < N) s += cnt[i]; }
  }
  sh[t] = s; __syncthreads();
  for (int off = 128; off > 0; off >>= 1){
    if (t < off) sh[t] += sh[t + off];
    __syncthreads();
  }
  if (t == 0) blockSums[blockIdx.x] = sh[0];
}

// 2b) exclusive scan of block sums (nb <= 256)
__global__ __launch_bounds__(256) void k_scan2(const int* __restrict__ blockSums,
    int* __restrict__ blockOff, int nb){
  __shared__ int sh[256];
  int t = threadIdx.x;
  int v = (t < nb) ? blockSums[t] : 0;
  sh[t] = v; __syncthreads();
  for (int off = 1; off < 256; off <<= 1){
    int x = (t >= off) ? sh[t - off] : 0;
    __syncthreads();
    sh[t] += x;
    __syncthreads();
  }
  if (t < nb) blockOff[t] = sh[t] - v;
}

// 2c) local scan + offset -> row_ptr, cursor; fused dinv = rsqrt(deg)
__global__ __launch_bounds__(256) void k_scan3(const int* __restrict__ cnt,
    const int* __restrict__ blockOff, int* __restrict__ row_ptr,
    int* __restrict__ cursor, float* __restrict__ dinv, int N, int E){
  __shared__ int sh[256];
  int t = threadIdx.x;
  int base = blockIdx.x * SCHUNK + t * 8;
  int v[8]; int s = 0;
  #pragma unroll
  for (int j = 0; j < 8; j++){
    int i = base + j;
    v[j] = (i < N) ? cnt[i] : 0;
    s += v[j];
  }
  sh[t] = s; __syncthreads();
  for (int off = 1; off < 256; off <<= 1){
    int x = (t >= off) ? sh[t - off] : 0;
    __syncthreads();
    sh[t] += x;
    __syncthreads();
  }
  int excl = blockOff[blockIdx.x] + sh[t] - s;
  #pragma unroll
  for (int j = 0; j < 8; j++){
    int i = base + j;
    if (i < N){
      row_ptr[i] = excl;
      cursor[i]  = excl;
      dinv[i]    = rsqrtf((float)v[j] + 1.0f);
    }
    excl += v[j];
  }
  if (blockIdx.x == 0 && t == 0) row_ptr[N] = E;
}

// 3) scatter edges into CSR (order within a node is arbitrary -> fp32 sum reorder ok)
__global__ void k_fill(const int* __restrict__ src, const int* __restrict__ dst,
                       int* __restrict__ cursor, int* __restrict__ col, int E){
  int e = blockIdx.x * blockDim.x + threadIdx.x;
  if (e < E){
    int pos = atomicAdd(&cursor[dst[e]], 1);
    col[pos] = src[e];
  }
}

// 5) fp32 GEMM: C[M,128] = A[M,128] @ W[128,128]
//    BM=64, BK=32; block 256 threads; thread = 8 rows x 4 cols micro-tile.
__global__ __launch_bounds__(256) void gemm128(const float* __restrict__ A,
    const float* __restrict__ W, float* __restrict__ C, int M){
  __shared__ float Ws[32 * 128];   // 16 KB, [k][col] linear
  __shared__ float At[32 * 64];    // 8 KB,  [k][row]
  int t = threadIdx.x;
  int rowBase = blockIdx.x * 64;
  int c0 = (t & 31) * 4;
  int r0 = (t >> 5) * 8;
  float acc[8][4] = {};
  for (int k0 = 0; k0 < 128; k0 += 32){
    const float* wt = W + k0 * 128;
    #pragma unroll
    for (int j = 0; j < 4; j++){
      int idx = j * 1024 + t * 4;
      *(float4*)&Ws[idx] = *(const float4*)&wt[idx];
    }
    #pragma unroll
    for (int j = 0; j < 2; j++){
      int lid = t + j * 256;        // 0..511
      int row = lid >> 3;
      int kk  = (lid & 7) * 4;
      int gr = rowBase + row; if (gr >= M) gr = M - 1;
      float4 v = *(const float4*)&A[(size_t)gr * D + k0 + kk];
      At[(kk + 0) * 64 + row] = v.x;
      At[(kk + 1) * 64 + row] = v.y;
      At[(kk + 2) * 64 + row] = v.z;
      At[(kk + 3) * 64 + row] = v.w;
    }
    __syncthreads();
    #pragma unroll
    for (int kk = 0; kk < 32; kk++){
      float4 b = *(float4*)&Ws[kk * 128 + c0];
      float4 a0 = *(float4*)&At[kk * 64 + r0];
      float4 a1 = *(float4*)&At[kk * 64 + r0 + 4];
      float av[8] = {a0.x, a0.y, a0.z, a0.w, a1.x, a1.y, a1.z, a1.w};
      #pragma unroll
      for (int r = 0; r < 8; r++){
        acc[r][0] += av[r] * b.x;
        acc[r][1] += av[r] * b.y;
        acc[r][2] += av[r] * b.z;
        acc[r][3] += av[r] * b.w;
      }
    }
    __syncthreads();
  }
  #pragma unroll
  for (int r = 0; r < 8; r++){
    int gr = rowBase + r0 + r;
    if (gr < M) *(float4*)&C[(size_t)gr * D + c0] = *(float4*)&acc[r][0];
  }
}

// 6) CSR aggregation: out[i] = sum_{s in N(i)} t[s]*dinv[s]*dinv[i] + t[i]*dinv[i]^2 + b; opt relu
__global__ __launch_bounds__(128) void k_agg(const float* __restrict__ t,
    const int* __restrict__ row_ptr, const int* __restrict__ col,
    const float* __restrict__ dinv, const float* __restrict__ bias,
    float* __restrict__ out, int relu){
  int i = blockIdx.x;
  int d = threadIdx.x;
  __shared__ int   scol[128];
  __shared__ float sw[128];
  float di = dinv[i];
  float acc = t[(size_t)i * D + d] * di * di + bias[d];   // self-loop + bias
  int beg = row_ptr[i], end = row_ptr[i + 1];
  for (int base = beg; base < end; base += 128){
    int m = end - base; if (m > 128) m = 128;
    if (d < m){ int s = col[base + d]; scol[d] = s; sw[d] = dinv[s] * di; }
    __syncthreads();
    for (int j = 0; j < m; j++)
      acc += t[(size_t)scol[j] * D + d] * sw[j];
    __syncthreads();
  }
  out[(size_t)i * D + d] = relu ? fmaxf(acc, 0.0f) : acc;
}

// 7) chunked segment-max into ordered-uint atomicMax (batch is sorted)
__global__ __launch_bounds__(128) void k_pool(const float* __restrict__ h,
    const int* __restrict__ batch, unsigned* __restrict__ pk, int N){
  int d = threadIdx.x;
  int n0 = blockIdx.x * 128;
  int nEnd = n0 + 128; if (nEnd > N) nEnd = N;
  float cur = -FLT_MAX;
  int curg = batch[n0];
  for (int n = n0; n < nEnd; n++){
    int g = batch[n];
    if (g != curg){
      atomicMax(&pk[curg * D + d], fkey(cur));
      cur = -FLT_MAX; curg = g;
    }
    cur = fmaxf(cur, h[(size_t)n * D + d]);
  }
  atomicMax(&pk[curg * D + d], fkey(cur));
}

// 8) final: out[64,2] = pooled @ Wf + bf
__global__ __launch_bounds__(128) void k_final(const unsigned* __restrict__ pk,
    const float* __restrict__ Wf, const float* __restrict__ bf,
    float* __restrict__ out){
  int t = threadIdx.x;            // 0..127
  int g = t >> 1, c = t & 1;
  float s = bf[c];
  for (int k = 0; k < D; k++)
    s += funkey(pk[g * D + k]) * Wf[k * 2 + c];
  out[g * 2 + c] = s;
}

extern "C" void kernel_launch(void* const* d_in, const int* in_sizes, int n_in,
                              void* d_out, int out_size, void* d_ws, size_t ws_size,
                              hipStream_t stream){
  const float* x   = (const float*)d_in[0];
  const int*   ei  = (const int*)d_in[1];
  const int*   bat = (const int*)d_in[2];
  const float* W0  = (const float*)d_in[3];
  const float* b0  = (const float*)d_in[4];
  const float* W1  = (const float*)d_in[5];
  const float* b1  = (const float*)d_in[6];
  const float* W2  = (const float*)d_in[7];
  const float* b2  = (const float*)d_in[8];
  const float* Wf  = (const float*)d_in[9];
  const float* bf  = (const float*)d_in[10];
  int N = in_sizes[0] / D;
  int E = in_sizes[1] / 2;
  const int* srcp = ei;
  const int* dstp = ei + E;
  int nb = (N + SCHUNK - 1) / SCHUNK;

  char* p = (char*)d_ws;
  auto alloc = [&](size_t bytes)->char*{
    char* r = p; p += (bytes + 255) & ~(size_t)255; return r;
  };
  float*    dinv    = (float*)alloc((size_t)N * 4);
  int*      cnt     = (int*)alloc((size_t)N * 4);
  int*      row_ptr = (int*)alloc((size_t)(N + 1) * 4);
  int*      cursor  = (int*)alloc((size_t)N * 4);
  int*      col     = (int*)alloc((size_t)E * 4);
  float*    tmp     = (float*)alloc((size_t)N * D * 4);
  float*    hbuf    = (float*)alloc((size_t)N * D * 4);
  unsigned* pk      = (unsigned*)alloc((size_t)NGRAPHS * D * 4);
  int*      bsums   = (int*)alloc((size_t)nb * 4);
  int*      boff    = (int*)alloc((size_t)nb * 4);

  hipMemsetAsync(cnt, 0, (size_t)N * 4, stream);
  hipMemsetAsync(pk, 0, (size_t)NGRAPHS * D * 4, stream);

  k_hist<<<(E + 255) / 256, 256, 0, stream>>>(dstp, cnt, E);
  k_scan1<<<nb, 256, 0, stream>>>(cnt, bsums, N);
  k_scan2<<<1, 256, 0, stream>>>(bsums, boff, nb);
  k_scan3<<<nb, 256, 0, stream>>>(cnt, boff, row_ptr, cursor, dinv, N, E);
  k_fill<<<(E + 255) / 256, 256, 0, stream>>>(srcp, dstp, cursor, col, E);

  int gblocks = (N + 63) / 64;
  // layer 0
  gemm128<<<gblocks, 256, 0, stream>>>(x, W0, tmp, N);
  k_agg<<<N, 128, 0, stream>>>(tmp, row_ptr, col, dinv, b0, hbuf, 1);
  // layer 1
  gemm128<<<gblocks, 256, 0, stream>>>(hbuf, W1, tmp, N);
  k_agg<<<N, 128, 0, stream>>>(tmp, row_ptr, col, dinv, b1, hbuf, 1);
  // layer 2 (no relu)
  gemm128<<<gblocks, 256, 0, stream>>>(hbuf, W2, tmp, N);
  k_agg<<<N, 128, 0, stream>>>(tmp, row_ptr, col, dinv, b2, hbuf, 0);
  // pool + classifier
  k_pool<<<(N + 127) / 128, 128, 0, stream>>>(hbuf, bat, pk, N);
  k_final<<<1, 128, 0, stream>>>(pk, Wf, bf, (float*)d_out);
}

// Round 3
// 844.300 us; speedup vs baseline: 1.2120x; 1.0024x over previous
//
#include <hip/hip_runtime.h>
#include <hip/hip_bf16.h>
#include <float.h>

#define D 128
#define NGRAPHS 64
#define SCHUNK 2048   // scan chunk per block (256 threads x 8)

// ---- ordered-float encoding for atomicMax on unsigned ----
__device__ __forceinline__ unsigned fkey(float f){
  unsigned u = __float_as_uint(f);
  return (u & 0x80000000u) ? ~u : (u | 0x80000000u);
}
__device__ __forceinline__ float funkey(unsigned k){
  unsigned u = (k & 0x80000000u) ? (k ^ 0x80000000u) : ~k;
  return __uint_as_float(u);
}

// 1) histogram of dst (deg = cnt + 1 for self-loop)
__global__ void k_hist(const int* __restrict__ dst, int* __restrict__ cnt, int E){
  int e = blockIdx.x * blockDim.x + threadIdx.x;
  if (e < E) atomicAdd(&cnt[dst[e]], 1);
}

// 2a) per-block sums over 2048-elem chunks
__global__ __launch_bounds__(256) void k_scan1(const int* __restrict__ cnt,
    int* __restrict__ blockSums, int N){
  __shared__ int sh[256];
  int t = threadIdx.x;
  int base = blockIdx.x * SCHUNK + t * 8;
  int s = 0;
  if (base + 7 < N){
    int4 a = *(const int4*)&cnt[base];
    int4 b = *(const int4*)&cnt[base + 4];
    s = a.x + a.y + a.z + a.w + b.x + b.y + b.z + b.w;
  } else {
    for (int j = 0; j < 8; j++){ int i = base + j; if (i < N) s += cnt[i]; }
  }
  sh[t] = s; __syncthreads();
  for (int off = 128; off > 0; off >>= 1){
    if (t < off) sh[t] += sh[t + off];
    __syncthreads();
  }
  if (t == 0) blockSums[blockIdx.x] = sh[0];
}

// 2b) exclusive scan of block sums (nb <= 256)
__global__ __launch_bounds__(256) void k_scan2(const int* __restrict__ blockSums,
    int* __restrict__ blockOff, int nb){
  __shared__ int sh[256];
  int t = threadIdx.x;
  int v = (t < nb) ? blockSums[t] : 0;
  sh[t] = v; __syncthreads();
  for (int off = 1; off < 256; off <<= 1){
    int x = (t >= off) ? sh[t - off] : 0;
    __syncthreads();
    sh[t] += x;
    __syncthreads();
  }
  if (t < nb) blockOff[t] = sh[t] - v;
}

// 2c) local scan + offset -> row_ptr, cursor; fused dinv = rsqrt(deg)
__global__ __launch_bounds__(256) void k_scan3(const int* __restrict__ cnt,
    const int* __restrict__ blockOff, int* __restrict__ row_ptr,
    int* __restrict__ cursor, float* __restrict__ dinv, int N, int E){
  __shared__ int sh[256];
  int t = threadIdx.x;
  int base = blockIdx.x * SCHUNK + t * 8;
  int v[8]; int s = 0;
  #pragma unroll
  for (int j = 0; j < 8; j++){
    int i = base + j;
    v[j] = (i < N) ? cnt[i] : 0;
    s += v[j];
  }
  sh[t] = s; __syncthreads();
  for (int off = 1; off < 256; off <<= 1){
    int x = (t >= off) ? sh[t - off] : 0;
    __syncthreads();
    sh[t] += x;
    __syncthreads();
  }
  int excl = blockOff[blockIdx.x] + sh[t] - s;
  #pragma unroll
  for (int j = 0; j < 8; j++){
    int i = base + j;
    if (i < N){
      row_ptr[i] = excl;
      cursor[i]  = excl;
      dinv[i]    = rsqrtf((float)v[j] + 1.0f);
    }
    excl += v[j];
  }
  if (blockIdx.x == 0 && t == 0) row_ptr[N] = E;
}

// 3) scatter edges into CSR (order within a node is arbitrary -> fp32 sum reorder ok)
__global__ void k_fill(const int* __restrict__ src, const int* __restrict__ dst,
                       int* __restrict__ cursor, int* __restrict__ col, int E){
  int e = blockIdx.x * blockDim.x + threadIdx.x;
  if (e < E){
    int pos = atomicAdd(&cursor[dst[e]], 1);
    col[pos] = src[e];
  }
}

// 5) fp32 GEMM: C[M,128] = A[M,128] @ W[128,128]
//    BM=64, BK=32; block 256 threads; thread = 8 rows x 4 cols micro-tile.
__global__ __launch_bounds__(256) void gemm128(const float* __restrict__ A,
    const float* __restrict__ W, float* __restrict__ C, int M){
  __shared__ float Ws[32 * 128];   // 16 KB, [k][col] linear
  __shared__ float At[32 * 64];    // 8 KB,  [k][row]
  int t = threadIdx.x;
  int rowBase = blockIdx.x * 64;
  int c0 = (t & 31) * 4;
  int r0 = (t >> 5) * 8;
  float acc[8][4] = {};
  for (int k0 = 0; k0 < 128; k0 += 32){
    const float* wt = W + k0 * 128;
    #pragma unroll
    for (int j = 0; j < 4; j++){
      int idx = j * 1024 + t * 4;
      *(float4*)&Ws[idx] = *(const float4*)&wt[idx];
    }
    #pragma unroll
    for (int j = 0; j < 2; j++){
      int lid = t + j * 256;        // 0..511
      int row = lid >> 3;
      int kk  = (lid & 7) * 4;
      int gr = rowBase + row; if (gr >= M) gr = M - 1;
      float4 v = *(const float4*)&A[(size_t)gr * D + k0 + kk];
      At[(kk + 0) * 64 + row] = v.x;
      At[(kk + 1) * 64 + row] = v.y;
      At[(kk + 2) * 64 + row] = v.z;
      At[(kk + 3) * 64 + row] = v.w;
    }
    __syncthreads();
    #pragma unroll
    for (int kk = 0; kk < 32; kk++){
      float4 b = *(float4*)&Ws[kk * 128 + c0];
      float4 a0 = *(float4*)&At[kk * 64 + r0];
      float4 a1 = *(float4*)&At[kk * 64 + r0 + 4];
      float av[8] = {a0.x, a0.y, a0.z, a0.w, a1.x, a1.y, a1.z, a1.w};
      #pragma unroll
      for (int r = 0; r < 8; r++){
        acc[r][0] += av[r] * b.x;
        acc[r][1] += av[r] * b.y;
        acc[r][2] += av[r] * b.z;
        acc[r][3] += av[r] * b.w;
      }
    }
    __syncthreads();
  }
  #pragma unroll
  for (int r = 0; r < 8; r++){
    int gr = rowBase + r0 + r;
    if (gr < M) *(float4*)&C[(size_t)gr * D + c0] = *(float4*)&acc[r][0];
  }
}

// 6) CSR aggregation, float4-vectorized, 4 neighbor-ways.
//    thread = (way = t>>5, colquad = t&31); each way processes neighbors
//    j = way, way+4, ...; float4 gather per lane (1 KB / wave-instruction).
//    out[i] = sum_{s in N(i)} t[s]*dinv[s]*dinv[i] + t[i]*dinv[i]^2 + b; opt relu
__global__ __launch_bounds__(128) void k_agg(const float* __restrict__ t,
    const int* __restrict__ row_ptr, const int* __restrict__ col,
    const float* __restrict__ dinv, const float* __restrict__ bias,
    float* __restrict__ out, int relu){
  int i = blockIdx.x;
  int tid = threadIdx.x;
  int cq  = (tid & 31) * 4;   // starting col of this thread's float4
  int way = tid >> 5;         // 0..3
  __shared__ int   soff[128];   // neighbor row offsets, pre-multiplied by D
  __shared__ float sw[128];     // neighbor weights
  __shared__ float red[3][32][4];
  float di = dinv[i];
  int beg = row_ptr[i], end = row_ptr[i + 1];
  float ax = 0.f, ay = 0.f, az = 0.f, aw = 0.f;
  for (int base = beg; base < end; base += 128){
    int m = end - base; if (m > 128) m = 128;
    if (tid < m){
      int s = col[base + tid];
      soff[tid] = s * D;
      sw[tid]   = dinv[s] * di;
    }
    __syncthreads();
    for (int j = way; j < m; j += 4){
      float w = sw[j];
      float4 v = *(const float4*)&t[(size_t)soff[j] + cq];
      ax += v.x * w; ay += v.y * w; az += v.z * w; aw += v.w * w;
    }
    __syncthreads();
  }
  int cqi = tid & 31;
  if (way != 0){
    red[way - 1][cqi][0] = ax; red[way - 1][cqi][1] = ay;
    red[way - 1][cqi][2] = az; red[way - 1][cqi][3] = aw;
  }
  __syncthreads();
  if (way == 0){
    float4 self = *(const float4*)&t[(size_t)i * D + cq];
    float4 bs   = *(const float4*)&bias[cq];
    float dii = di * di;
    float ox = ax + red[0][cqi][0] + red[1][cqi][0] + red[2][cqi][0] + self.x * dii + bs.x;
    float oy = ay + red[0][cqi][1] + red[1][cqi][1] + red[2][cqi][1] + self.y * dii + bs.y;
    float oz = az + red[0][cqi][2] + red[1][cqi][2] + red[2][cqi][2] + self.z * dii + bs.z;
    float ow = aw + red[0][cqi][3] + red[1][cqi][3] + red[2][cqi][3] + self.w * dii + bs.w;
    if (relu){
      ox = fmaxf(ox, 0.f); oy = fmaxf(oy, 0.f);
      oz = fmaxf(oz, 0.f); ow = fmaxf(ow, 0.f);
    }
    float4 o = {ox, oy, oz, ow};
    *(float4*)&out[(size_t)i * D + cq] = o;
  }
}

// 7) chunked segment-max into ordered-uint atomicMax (batch is sorted)
__global__ __launch_bounds__(128) void k_pool(const float* __restrict__ h,
    const int* __restrict__ batch, unsigned* __restrict__ pk, int N){
  int d = threadIdx.x;
  int n0 = blockIdx.x * 128;
  int nEnd = n0 + 128; if (nEnd > N) nEnd = N;
  float cur = -FLT_MAX;
  int curg = batch[n0];
  for (int n = n0; n < nEnd; n++){
    int g = batch[n];
    if (g != curg){
      atomicMax(&pk[curg * D + d], fkey(cur));
      cur = -FLT_MAX; curg = g;
    }
    cur = fmaxf(cur, h[(size_t)n * D + d]);
  }
  atomicMax(&pk[curg * D + d], fkey(cur));
}

// 8) final: out[64,2] = pooled @ Wf + bf
__global__ __launch_bounds__(128) void k_final(const unsigned* __restrict__ pk,
    const float* __restrict__ Wf, const float* __restrict__ bf,
    float* __restrict__ out){
  int t = threadIdx.x;            // 0..127
  int g = t >> 1, c = t & 1;
  float s = bf[c];
  for (int k = 0; k < D; k++)
    s += funkey(pk[g * D + k]) * Wf[k * 2 + c];
  out[g * 2 + c] = s;
}

extern "C" void kernel_launch(void* const* d_in, const int* in_sizes, int n_in,
                              void* d_out, int out_size, void* d_ws, size_t ws_size,
                              hipStream_t stream){
  const float* x   = (const float*)d_in[0];
  const int*   ei  = (const int*)d_in[1];
  const int*   bat = (const int*)d_in[2];
  const float* W0  = (const float*)d_in[3];
  const float* b0  = (const float*)d_in[4];
  const float* W1  = (const float*)d_in[5];
  const float* b1  = (const float*)d_in[6];
  const float* W2  = (const float*)d_in[7];
  const float* b2  = (const float*)d_in[8];
  const float* Wf  = (const float*)d_in[9];
  const float* bf  = (const float*)d_in[10];
  int N = in_sizes[0] / D;
  int E = in_sizes[1] / 2;
  const int* srcp = ei;
  const int* dstp = ei + E;
  int nb = (N + SCHUNK - 1) / SCHUNK;

  char* p = (char*)d_ws;
  auto alloc = [&](size_t bytes)->char*{
    char* r = p; p += (bytes + 255) & ~(size_t)255; return r;
  };
  float*    dinv    = (float*)alloc((size_t)N * 4);
  int*      cnt     = (int*)alloc((size_t)N * 4);
  int*      row_ptr = (int*)alloc((size_t)(N + 1) * 4);
  int*      cursor  = (int*)alloc((size_t)N * 4);
  int*      col     = (int*)alloc((size_t)E * 4);
  float*    tmp     = (float*)alloc((size_t)N * D * 4);
  float*    hbuf    = (float*)alloc((size_t)N * D * 4);
  unsigned* pk      = (unsigned*)alloc((size_t)NGRAPHS * D * 4);
  int*      bsums   = (int*)alloc((size_t)nb * 4);
  int*      boff    = (int*)alloc((size_t)nb * 4);

  hipMemsetAsync(cnt, 0, (size_t)N * 4, stream);
  hipMemsetAsync(pk, 0, (size_t)NGRAPHS * D * 4, stream);

  k_hist<<<(E + 255) / 256, 256, 0, stream>>>(dstp, cnt, E);
  k_scan1<<<nb, 256, 0, stream>>>(cnt, bsums, N);
  k_scan2<<<1, 256, 0, stream>>>(bsums, boff, nb);
  k_scan3<<<nb, 256, 0, stream>>>(cnt, boff, row_ptr, cursor, dinv, N, E);
  k_fill<<<(E + 255) / 256, 256, 0, stream>>>(srcp, dstp, cursor, col, E);

  int gblocks = (N + 63) / 64;
  // layer 0
  gemm128<<<gblocks, 256, 0, stream>>>(x, W0, tmp, N);
  k_agg<<<N, 128, 0, stream>>>(tmp, row_ptr, col, dinv, b0, hbuf, 1);
  // layer 1
  gemm128<<<gblocks, 256, 0, stream>>>(hbuf, W1, tmp, N);
  k_agg<<<N, 128, 0, stream>>>(tmp, row_ptr, col, dinv, b1, hbuf, 1);
  // layer 2 (no relu)
  gemm128<<<gblocks, 256, 0, stream>>>(hbuf, W2, tmp, N);
  k_agg<<<N, 128, 0, stream>>>(tmp, row_ptr, col, dinv, b2, hbuf, 0);
  // pool + classifier
  k_pool<<<(N + 127) / 128, 128, 0, stream>>>(hbuf, bat, pk, N);
  k_final<<<1, 128, 0, stream>>>(pk, Wf, bf, (float*)d_out);
}

// Round 4
// 734.470 us; speedup vs baseline: 1.3933x; 1.1495x over previous
//
#include <hip/hip_runtime.h>
#include <hip/hip_bf16.h>
#include <hip/hip_fp16.h>
#include <float.h>

#define D 128
#define NGRAPHS 64
#define SCHUNK 2048   // scan chunk per block (256 threads x 8)

// ---- ordered-float encoding for atomicMax on unsigned ----
__device__ __forceinline__ unsigned fkey(float f){
  unsigned u = __float_as_uint(f);
  return (u & 0x80000000u) ? ~u : (u | 0x80000000u);
}
__device__ __forceinline__ float funkey(unsigned k){
  unsigned u = (k & 0x80000000u) ? (k ^ 0x80000000u) : ~k;
  return __uint_as_float(u);
}

// 1) histogram of dst (deg = cnt + 1 for self-loop)
__global__ void k_hist(const int* __restrict__ dst, int* __restrict__ cnt, int E){
  int e = blockIdx.x * blockDim.x + threadIdx.x;
  if (e < E) atomicAdd(&cnt[dst[e]], 1);
}

// 2a) per-block sums over 2048-elem chunks
__global__ __launch_bounds__(256) void k_scan1(const int* __restrict__ cnt,
    int* __restrict__ blockSums, int N){
  __shared__ int sh[256];
  int t = threadIdx.x;
  int base = blockIdx.x * SCHUNK + t * 8;
  int s = 0;
  if (base + 7 < N){
    int4 a = *(const int4*)&cnt[base];
    int4 b = *(const int4*)&cnt[base + 4];
    s = a.x + a.y + a.z + a.w + b.x + b.y + b.z + b.w;
  } else {
    for (int j = 0; j < 8; j++){ int i = base + j; if (i < N) s += cnt[i]; }
  }
  sh[t] = s; __syncthreads();
  for (int off = 128; off > 0; off >>= 1){
    if (t < off) sh[t] += sh[t + off];
    __syncthreads();
  }
  if (t == 0) blockSums[blockIdx.x] = sh[0];
}

// 2b) exclusive scan of block sums (nb <= 256)
__global__ __launch_bounds__(256) void k_scan2(const int* __restrict__ blockSums,
    int* __restrict__ blockOff, int nb){
  __shared__ int sh[256];
  int t = threadIdx.x;
  int v = (t < nb) ? blockSums[t] : 0;
  sh[t] = v; __syncthreads();
  for (int off = 1; off < 256; off <<= 1){
    int x = (t >= off) ? sh[t - off] : 0;
    __syncthreads();
    sh[t] += x;
    __syncthreads();
  }
  if (t < nb) blockOff[t] = sh[t] - v;
}

// 2c) local scan + offset -> row_ptr, cursor; fused dinv = rsqrt(deg)
__global__ __launch_bounds__(256) void k_scan3(const int* __restrict__ cnt,
    const int* __restrict__ blockOff, int* __restrict__ row_ptr,
    int* __restrict__ cursor, float* __restrict__ dinv, int N, int E){
  __shared__ int sh[256];
  int t = threadIdx.x;
  int base = blockIdx.x * SCHUNK + t * 8;
  int v[8]; int s = 0;
  #pragma unroll
  for (int j = 0; j < 8; j++){
    int i = base + j;
    v[j] = (i < N) ? cnt[i] : 0;
    s += v[j];
  }
  sh[t] = s; __syncthreads();
  for (int off = 1; off < 256; off <<= 1){
    int x = (t >= off) ? sh[t - off] : 0;
    __syncthreads();
    sh[t] += x;
    __syncthreads();
  }
  int excl = blockOff[blockIdx.x] + sh[t] - s;
  #pragma unroll
  for (int j = 0; j < 8; j++){
    int i = base + j;
    if (i < N){
      row_ptr[i] = excl;
      cursor[i]  = excl;
      dinv[i]    = rsqrtf((float)v[j] + 1.0f);
    }
    excl += v[j];
  }
  if (blockIdx.x == 0 && t == 0) row_ptr[N] = E;
}

// 3) scatter edges into CSR (order within a node is arbitrary -> fp32 sum reorder ok)
__global__ void k_fill(const int* __restrict__ src, const int* __restrict__ dst,
                       int* __restrict__ cursor, int* __restrict__ col, int E){
  int e = blockIdx.x * blockDim.x + threadIdx.x;
  if (e < E){
    int pos = atomicAdd(&cursor[dst[e]], 1);
    col[pos] = src[e];
  }
}

// 5) fp32 GEMM: C[M,128] = A[M,128] @ W[128,128], output packed fp16.
//    BM=64, BK=32; block 256 threads; thread = 8 rows x 4 cols micro-tile.
__global__ __launch_bounds__(256) void gemm128(const float* __restrict__ A,
    const float* __restrict__ W, __half* __restrict__ C, int M){
  __shared__ float Ws[32 * 128];   // 16 KB, [k][col] linear
  __shared__ float At[32 * 64];    // 8 KB,  [k][row]
  int t = threadIdx.x;
  int rowBase = blockIdx.x * 64;
  int c0 = (t & 31) * 4;
  int r0 = (t >> 5) * 8;
  float acc[8][4] = {};
  for (int k0 = 0; k0 < 128; k0 += 32){
    const float* wt = W + k0 * 128;
    #pragma unroll
    for (int j = 0; j < 4; j++){
      int idx = j * 1024 + t * 4;
      *(float4*)&Ws[idx] = *(const float4*)&wt[idx];
    }
    #pragma unroll
    for (int j = 0; j < 2; j++){
      int lid = t + j * 256;        // 0..511
      int row = lid >> 3;
      int kk  = (lid & 7) * 4;
      int gr = rowBase + row; if (gr >= M) gr = M - 1;
      float4 v = *(const float4*)&A[(size_t)gr * D + k0 + kk];
      At[(kk + 0) * 64 + row] = v.x;
      At[(kk + 1) * 64 + row] = v.y;
      At[(kk + 2) * 64 + row] = v.z;
      At[(kk + 3) * 64 + row] = v.w;
    }
    __syncthreads();
    #pragma unroll
    for (int kk = 0; kk < 32; kk++){
      float4 b = *(float4*)&Ws[kk * 128 + c0];
      float4 a0 = *(float4*)&At[kk * 64 + r0];
      float4 a1 = *(float4*)&At[kk * 64 + r0 + 4];
      float av[8] = {a0.x, a0.y, a0.z, a0.w, a1.x, a1.y, a1.z, a1.w};
      #pragma unroll
      for (int r = 0; r < 8; r++){
        acc[r][0] += av[r] * b.x;
        acc[r][1] += av[r] * b.y;
        acc[r][2] += av[r] * b.z;
        acc[r][3] += av[r] * b.w;
      }
    }
    __syncthreads();
  }
  #pragma unroll
  for (int r = 0; r < 8; r++){
    int gr = rowBase + r0 + r;
    if (gr < M){
      __half2 p0 = __floats2half2_rn(acc[r][0], acc[r][1]);
      __half2 p1 = __floats2half2_rn(acc[r][2], acc[r][3]);
      uint2 u;
      u.x = *(unsigned*)&p0;
      u.y = *(unsigned*)&p1;
      *(uint2*)&C[(size_t)gr * D + c0] = u;   // 8 B = 4 halves
    }
  }
}

// 6) CSR aggregation over fp16 rows, fp32 accumulate, 4 neighbor-ways.
//    thread = (way = t>>5, colquad = t&31); each way processes neighbors
//    j = way, way+4, ...; uint2 (=4 halves) gather per lane.
//    out[i] = sum_{s in N(i)} t[s]*dinv[s]*dinv[i] + t[i]*dinv[i]^2 + b; opt relu
__global__ __launch_bounds__(128) void k_agg(const __half* __restrict__ t,
    const int* __restrict__ row_ptr, const int* __restrict__ col,
    const float* __restrict__ dinv, const float* __restrict__ bias,
    float* __restrict__ out, int relu){
  int i = blockIdx.x;
  int tid = threadIdx.x;
  int cq  = (tid & 31) * 4;   // starting col of this thread's 4-col group
  int way = tid >> 5;         // 0..3
  __shared__ int   soff[128];   // neighbor row offsets in halves (s*D)
  __shared__ float sw[128];     // neighbor weights
  __shared__ float red[3][32][4];
  float di = dinv[i];
  int beg = row_ptr[i], end = row_ptr[i + 1];
  float ax = 0.f, ay = 0.f, az = 0.f, aw = 0.f;
  for (int base = beg; base < end; base += 128){
    int m = end - base; if (m > 128) m = 128;
    if (tid < m){
      int s = col[base + tid];
      soff[tid] = s * D;
      sw[tid]   = dinv[s] * di;
    }
    __syncthreads();
    for (int j = way; j < m; j += 4){
      float w = sw[j];
      uint2 u = *(const uint2*)&t[(size_t)soff[j] + cq];
      __half2 p0 = *(__half2*)&u.x;
      __half2 p1 = *(__half2*)&u.y;
      float2 f0 = __half22float2(p0);
      float2 f1 = __half22float2(p1);
      ax += f0.x * w; ay += f0.y * w; az += f1.x * w; aw += f1.y * w;
    }
    __syncthreads();
  }
  int cqi = tid & 31;
  if (way != 0){
    red[way - 1][cqi][0] = ax; red[way - 1][cqi][1] = ay;
    red[way - 1][cqi][2] = az; red[way - 1][cqi][3] = aw;
  }
  __syncthreads();
  if (way == 0){
    uint2 su = *(const uint2*)&t[(size_t)i * D + cq];
    __half2 s0 = *(__half2*)&su.x;
    __half2 s1 = *(__half2*)&su.y;
    float2 sf0 = __half22float2(s0);
    float2 sf1 = __half22float2(s1);
    float4 bs = *(const float4*)&bias[cq];
    float dii = di * di;
    float ox = ax + red[0][cqi][0] + red[1][cqi][0] + red[2][cqi][0] + sf0.x * dii + bs.x;
    float oy = ay + red[0][cqi][1] + red[1][cqi][1] + red[2][cqi][1] + sf0.y * dii + bs.y;
    float oz = az + red[0][cqi][2] + red[1][cqi][2] + red[2][cqi][2] + sf1.x * dii + bs.z;
    float ow = aw + red[0][cqi][3] + red[1][cqi][3] + red[2][cqi][3] + sf1.y * dii + bs.w;
    if (relu){
      ox = fmaxf(ox, 0.f); oy = fmaxf(oy, 0.f);
      oz = fmaxf(oz, 0.f); ow = fmaxf(ow, 0.f);
    }
    float4 o = {ox, oy, oz, ow};
    *(float4*)&out[(size_t)i * D + cq] = o;
  }
}

// 7) chunked segment-max into ordered-uint atomicMax (batch is sorted)
__global__ __launch_bounds__(128) void k_pool(const float* __restrict__ h,
    const int* __restrict__ batch, unsigned* __restrict__ pk, int N){
  int d = threadIdx.x;
  int n0 = blockIdx.x * 128;
  int nEnd = n0 + 128; if (nEnd > N) nEnd = N;
  float cur = -FLT_MAX;
  int curg = batch[n0];
  for (int n = n0; n < nEnd; n++){
    int g = batch[n];
    if (g != curg){
      atomicMax(&pk[curg * D + d], fkey(cur));
      cur = -FLT_MAX; curg = g;
    }
    cur = fmaxf(cur, h[(size_t)n * D + d]);
  }
  atomicMax(&pk[curg * D + d], fkey(cur));
}

// 8) final: out[64,2] = pooled @ Wf + bf
__global__ __launch_bounds__(128) void k_final(const unsigned* __restrict__ pk,
    const float* __restrict__ Wf, const float* __restrict__ bf,
    float* __restrict__ out){
  int t = threadIdx.x;            // 0..127
  int g = t >> 1, c = t & 1;
  float s = bf[c];
  for (int k = 0; k < D; k++)
    s += funkey(pk[g * D + k]) * Wf[k * 2 + c];
  out[g * 2 + c] = s;
}

extern "C" void kernel_launch(void* const* d_in, const int* in_sizes, int n_in,
                              void* d_out, int out_size, void* d_ws, size_t ws_size,
                              hipStream_t stream){
  const float* x   = (const float*)d_in[0];
  const int*   ei  = (const int*)d_in[1];
  const int*   bat = (const int*)d_in[2];
  const float* W0  = (const float*)d_in[3];
  const float* b0  = (const float*)d_in[4];
  const float* W1  = (const float*)d_in[5];
  const float* b1  = (const float*)d_in[6];
  const float* W2  = (const float*)d_in[7];
  const float* b2  = (const float*)d_in[8];
  const float* Wf  = (const float*)d_in[9];
  const float* bf  = (const float*)d_in[10];
  int N = in_sizes[0] / D;
  int E = in_sizes[1] / 2;
  const int* srcp = ei;
  const int* dstp = ei + E;
  int nb = (N + SCHUNK - 1) / SCHUNK;

  char* p = (char*)d_ws;
  auto alloc = [&](size_t bytes)->char*{
    char* r = p; p += (bytes + 255) & ~(size_t)255; return r;
  };
  float*    dinv    = (float*)alloc((size_t)N * 4);
  int*      cnt     = (int*)alloc((size_t)N * 4);
  int*      row_ptr = (int*)alloc((size_t)(N + 1) * 4);
  int*      cursor  = (int*)alloc((size_t)N * 4);
  int*      col     = (int*)alloc((size_t)E * 4);
  __half*   tmp     = (__half*)alloc((size_t)N * D * 2);
  float*    hbuf    = (float*)alloc((size_t)N * D * 4);
  unsigned* pk      = (unsigned*)alloc((size_t)NGRAPHS * D * 4);
  int*      bsums   = (int*)alloc((size_t)nb * 4);
  int*      boff    = (int*)alloc((size_t)nb * 4);

  hipMemsetAsync(cnt, 0, (size_t)N * 4, stream);
  hipMemsetAsync(pk, 0, (size_t)NGRAPHS * D * 4, stream);

  k_hist<<<(E + 255) / 256, 256, 0, stream>>>(dstp, cnt, E);
  k_scan1<<<nb, 256, 0, stream>>>(cnt, bsums, N);
  k_scan2<<<1, 256, 0, stream>>>(bsums, boff, nb);
  k_scan3<<<nb, 256, 0, stream>>>(cnt, boff, row_ptr, cursor, dinv, N, E);
  k_fill<<<(E + 255) / 256, 256, 0, stream>>>(srcp, dstp, cursor, col, E);

  int gblocks = (N + 63) / 64;
  // layer 0
  gemm128<<<gblocks, 256, 0, stream>>>(x, W0, tmp, N);
  k_agg<<<N, 128, 0, stream>>>(tmp, row_ptr, col, dinv, b0, hbuf, 1);
  // layer 1
  gemm128<<<gblocks, 256, 0, stream>>>(hbuf, W1, tmp, N);
  k_agg<<<N, 128, 0, stream>>>(tmp, row_ptr, col, dinv, b1, hbuf, 1);
  // layer 2 (no relu)
  gemm128<<<gblocks, 256, 0, stream>>>(hbuf, W2, tmp, N);
  k_agg<<<N, 128, 0, stream>>>(tmp, row_ptr, col, dinv, b2, hbuf, 0);
  // pool + classifier
  k_pool<<<(N + 127) / 128, 128, 0, stream>>>(hbuf, bat, pk, N);
  k_final<<<1, 128, 0, stream>>>(pk, Wf, bf, (float*)d_out);
}

// Round 5
// 610.639 us; speedup vs baseline: 1.6758x; 1.2028x over previous
//
#include <hip/hip_runtime.h>
#include <hip/hip_bf16.h>
#include <hip/hip_fp16.h>
#include <float.h>

#define D 128
#define NGRAPHS 64
#define BKSHIFT 9
#define BKNODES 512     // nodes per bucket
#define MAXBK 256       // max buckets (N<=131072)
#define PCH 4096        // edges per partition block (256 thr x 16)

// ---- ordered-float encoding for atomicMax on unsigned ----
__device__ __forceinline__ unsigned fkey(float f){
  unsigned u = __float_as_uint(f);
  return (u & 0x80000000u) ? ~u : (u | 0x80000000u);
}
__device__ __forceinline__ float funkey(unsigned k){
  unsigned u = (k & 0x80000000u) ? (k ^ 0x80000000u) : ~k;
  return __uint_as_float(u);
}

// A) bucket histogram: bcnt[b] = #edges with dst in bucket b
__global__ __launch_bounds__(256) void k_bhist(const int* __restrict__ dst,
    int* __restrict__ bcnt, int E){
  __shared__ int h[MAXBK];
  int t = threadIdx.x;
  for (int i = t; i < MAXBK; i += 256) h[i] = 0;
  __syncthreads();
  int e0 = blockIdx.x * PCH;
  #pragma unroll
  for (int j = 0; j < PCH / 256; j++){
    int e = e0 + t + j * 256;
    if (e < E) atomicAdd(&h[dst[e] >> BKSHIFT], 1);
  }
  __syncthreads();
  for (int i = t; i < MAXBK; i += 256) if (h[i]) atomicAdd(&bcnt[i], h[i]);
}

// B) scan bucket counts -> bOff[nbk+1], bCur; also row_ptr[N]=E
__global__ __launch_bounds__(256) void k_bscan(const int* __restrict__ bcnt,
    int* __restrict__ bOff, int* __restrict__ bCur, int* __restrict__ row_ptr,
    int nbk, int N, int E){
  __shared__ int sh[256];
  int t = threadIdx.x;
  int v = (t < nbk) ? bcnt[t] : 0;
  sh[t] = v; __syncthreads();
  for (int off = 1; off < 256; off <<= 1){
    int x = (t >= off) ? sh[t - off] : 0;
    __syncthreads();
    sh[t] += x;
    __syncthreads();
  }
  if (t < nbk){ int ex = sh[t] - v; bOff[t] = ex; bCur[t] = ex; }
  if (t == 0){ bOff[nbk] = E; row_ptr[N] = E; }
}

// C) partition edges into bucket-grouped epart[] with LDS-staged coalesced writes
__global__ __launch_bounds__(256) void k_part(const int* __restrict__ src,
    const int* __restrict__ dst, int* __restrict__ bCur,
    uint2* __restrict__ epart, int E){
  __shared__ int scnt[MAXBK], soff[MAXBK], sbase[MAXBK], scur[MAXBK];
  __shared__ int stmp[256];
  __shared__ uint2 stage[PCH];   // 32 KB
  int t = threadIdx.x;
  int e0 = blockIdx.x * PCH;
  int eN = E - e0; if (eN > PCH) eN = PCH;
  for (int i = t; i < MAXBK; i += 256){ scnt[i] = 0; scur[i] = 0; }
  __syncthreads();
  uint2 mye[PCH / 256];
  #pragma unroll
  for (int j = 0; j < PCH / 256; j++){
    int e = e0 + t + j * 256;
    if (e < E){
      mye[j].x = (unsigned)src[e];
      mye[j].y = (unsigned)dst[e];
      atomicAdd(&scnt[mye[j].y >> BKSHIFT], 1);
    }
  }
  __syncthreads();
  // exclusive scan of scnt (256 == MAXBK lanes)
  int v = scnt[t];
  stmp[t] = v; __syncthreads();
  for (int off = 1; off < 256; off <<= 1){
    int x = (t >= off) ? stmp[t - off] : 0;
    __syncthreads();
    stmp[t] += x;
    __syncthreads();
  }
  soff[t] = stmp[t] - v;
  // reserve this block's run in each bucket
  if (v > 0) sbase[t] = atomicAdd(&bCur[t], v);
  __syncthreads();
  // place edges into stage, grouped by bucket
  #pragma unroll
  for (int j = 0; j < PCH / 256; j++){
    int e = e0 + t + j * 256;
    if (e < E){
      int b = mye[j].y >> BKSHIFT;
      int l = atomicAdd(&scur[b], 1);
      stage[soff[b] + l] = mye[j];
    }
  }
  __syncthreads();
  // write out: consecutive threads -> consecutive slots within per-bucket runs
  for (int j = t; j < eN; j += 256){
    uint2 ed = stage[j];
    int b = (int)(ed.y >> BKSHIFT);
    epart[(size_t)sbase[b] + (j - soff[b])] = ed;
  }
}

// D) per-bucket CSR build: row_ptr, col, dinv — all state in LDS, confined writes
__global__ __launch_bounds__(256) void k_bfill(const uint2* __restrict__ epart,
    const int* __restrict__ bOff, int* __restrict__ row_ptr,
    int* __restrict__ col, float* __restrict__ dinv, int N){
  __shared__ int hc[BKNODES], off[BKNODES], cur[BKNODES];
  __shared__ int stmp[256];
  int b = blockIdx.x, t = threadIdx.x;
  int base = bOff[b], cntE = bOff[b + 1] - base;
  int node0 = b << BKSHIFT;
  int nloc = N - node0; if (nloc > BKNODES) nloc = BKNODES;
  for (int i = t; i < BKNODES; i += 256) hc[i] = 0;
  __syncthreads();
  for (int j = t; j < cntE; j += 256){
    uint2 ed = epart[(size_t)base + j];
    atomicAdd(&hc[ed.y - node0], 1);
  }
  __syncthreads();
  // exclusive scan of 512 via pairs on 256 threads
  int a0 = hc[2 * t], a1 = hc[2 * t + 1];
  int s = a0 + a1;
  stmp[t] = s; __syncthreads();
  for (int o = 1; o < 256; o <<= 1){
    int x = (t >= o) ? stmp[t - o] : 0;
    __syncthreads();
    stmp[t] += x;
    __syncthreads();
  }
  int ex = stmp[t] - s;
  off[2 * t] = ex; off[2 * t + 1] = ex + a0;
  __syncthreads();
  for (int i = t; i < nloc; i += 256){
    row_ptr[node0 + i] = base + off[i];
    dinv[node0 + i]    = rsqrtf((float)hc[i] + 1.0f);
    cur[i] = off[i];
  }
  __syncthreads();
  for (int j = t; j < cntE; j += 256){
    uint2 ed = epart[(size_t)base + j];
    int p = atomicAdd(&cur[ed.y - node0], 1);
    col[base + p] = (int)ed.x;
  }
}

// 5) fp32 GEMM: C[M,128] = A[M,128] @ W[128,128], output packed fp16.
__global__ __launch_bounds__(256) void gemm128(const float* __restrict__ A,
    const float* __restrict__ W, __half* __restrict__ C, int M){
  __shared__ float Ws[32 * 128];
  __shared__ float At[32 * 64];
  int t = threadIdx.x;
  int rowBase = blockIdx.x * 64;
  int c0 = (t & 31) * 4;
  int r0 = (t >> 5) * 8;
  float acc[8][4] = {};
  for (int k0 = 0; k0 < 128; k0 += 32){
    const float* wt = W + k0 * 128;
    #pragma unroll
    for (int j = 0; j < 4; j++){
      int idx = j * 1024 + t * 4;
      *(float4*)&Ws[idx] = *(const float4*)&wt[idx];
    }
    #pragma unroll
    for (int j = 0; j < 2; j++){
      int lid = t + j * 256;
      int row = lid >> 3;
      int kk  = (lid & 7) * 4;
      int gr = rowBase + row; if (gr >= M) gr = M - 1;
      float4 v = *(const float4*)&A[(size_t)gr * D + k0 + kk];
      At[(kk + 0) * 64 + row] = v.x;
      At[(kk + 1) * 64 + row] = v.y;
      At[(kk + 2) * 64 + row] = v.z;
      At[(kk + 3) * 64 + row] = v.w;
    }
    __syncthreads();
    #pragma unroll
    for (int kk = 0; kk < 32; kk++){
      float4 b = *(float4*)&Ws[kk * 128 + c0];
      float4 a0 = *(float4*)&At[kk * 64 + r0];
      float4 a1 = *(float4*)&At[kk * 64 + r0 + 4];
      float av[8] = {a0.x, a0.y, a0.z, a0.w, a1.x, a1.y, a1.z, a1.w};
      #pragma unroll
      for (int r = 0; r < 8; r++){
        acc[r][0] += av[r] * b.x;
        acc[r][1] += av[r] * b.y;
        acc[r][2] += av[r] * b.z;
        acc[r][3] += av[r] * b.w;
      }
    }
    __syncthreads();
  }
  #pragma unroll
  for (int r = 0; r < 8; r++){
    int gr = rowBase + r0 + r;
    if (gr < M){
      __half2 p0 = __floats2half2_rn(acc[r][0], acc[r][1]);
      __half2 p1 = __floats2half2_rn(acc[r][2], acc[r][3]);
      uint2 u;
      u.x = *(unsigned*)&p0;
      u.y = *(unsigned*)&p1;
      *(uint2*)&C[(size_t)gr * D + c0] = u;
    }
  }
}

// 6) CSR aggregation over fp16 rows, fp32 accumulate, 4 neighbor-ways.
__global__ __launch_bounds__(128) void k_agg(const __half* __restrict__ t,
    const int* __restrict__ row_ptr, const int* __restrict__ col,
    const float* __restrict__ dinv, const float* __restrict__ bias,
    float* __restrict__ out, int relu){
  int i = blockIdx.x;
  int tid = threadIdx.x;
  int cq  = (tid & 31) * 4;
  int way = tid >> 5;
  __shared__ int   soff[128];
  __shared__ float sw[128];
  __shared__ float red[3][32][4];
  float di = dinv[i];
  int beg = row_ptr[i], end = row_ptr[i + 1];
  float ax = 0.f, ay = 0.f, az = 0.f, aw = 0.f;
  for (int base = beg; base < end; base += 128){
    int m = end - base; if (m > 128) m = 128;
    if (tid < m){
      int s = col[base + tid];
      soff[tid] = s * D;
      sw[tid]   = dinv[s] * di;
    }
    __syncthreads();
    for (int j = way; j < m; j += 4){
      float w = sw[j];
      uint2 u = *(const uint2*)&t[(size_t)soff[j] + cq];
      __half2 p0 = *(__half2*)&u.x;
      __half2 p1 = *(__half2*)&u.y;
      float2 f0 = __half22float2(p0);
      float2 f1 = __half22float2(p1);
      ax += f0.x * w; ay += f0.y * w; az += f1.x * w; aw += f1.y * w;
    }
    __syncthreads();
  }
  int cqi = tid & 31;
  if (way != 0){
    red[way - 1][cqi][0] = ax; red[way - 1][cqi][1] = ay;
    red[way - 1][cqi][2] = az; red[way - 1][cqi][3] = aw;
  }
  __syncthreads();
  if (way == 0){
    uint2 su = *(const uint2*)&t[(size_t)i * D + cq];
    __half2 s0 = *(__half2*)&su.x;
    __half2 s1 = *(__half2*)&su.y;
    float2 sf0 = __half22float2(s0);
    float2 sf1 = __half22float2(s1);
    float4 bs = *(const float4*)&bias[cq];
    float dii = di * di;
    float ox = ax + red[0][cqi][0] + red[1][cqi][0] + red[2][cqi][0] + sf0.x * dii + bs.x;
    float oy = ay + red[0][cqi][1] + red[1][cqi][1] + red[2][cqi][1] + sf0.y * dii + bs.y;
    float oz = az + red[0][cqi][2] + red[1][cqi][2] + red[2][cqi][2] + sf1.x * dii + bs.z;
    float ow = aw + red[0][cqi][3] + red[1][cqi][3] + red[2][cqi][3] + sf1.y * dii + bs.w;
    if (relu){
      ox = fmaxf(ox, 0.f); oy = fmaxf(oy, 0.f);
      oz = fmaxf(oz, 0.f); ow = fmaxf(ow, 0.f);
    }
    float4 o = {ox, oy, oz, ow};
    *(float4*)&out[(size_t)i * D + cq] = o;
  }
}

// 7) chunked segment-max into ordered-uint atomicMax (batch is sorted)
__global__ __launch_bounds__(128) void k_pool(const float* __restrict__ h,
    const int* __restrict__ batch, unsigned* __restrict__ pk, int N){
  int d = threadIdx.x;
  int n0 = blockIdx.x * 128;
  int nEnd = n0 + 128; if (nEnd > N) nEnd = N;
  float cur = -FLT_MAX;
  int curg = batch[n0];
  for (int n = n0; n < nEnd; n++){
    int g = batch[n];
    if (g != curg){
      atomicMax(&pk[curg * D + d], fkey(cur));
      cur = -FLT_MAX; curg = g;
    }
    cur = fmaxf(cur, h[(size_t)n * D + d]);
  }
  atomicMax(&pk[curg * D + d], fkey(cur));
}

// 8) final: out[64,2] = pooled @ Wf + bf
__global__ __launch_bounds__(128) void k_final(const unsigned* __restrict__ pk,
    const float* __restrict__ Wf, const float* __restrict__ bf,
    float* __restrict__ out){
  int t = threadIdx.x;
  int g = t >> 1, c = t & 1;
  float s = bf[c];
  for (int k = 0; k < D; k++)
    s += funkey(pk[g * D + k]) * Wf[k * 2 + c];
  out[g * 2 + c] = s;
}

extern "C" void kernel_launch(void* const* d_in, const int* in_sizes, int n_in,
                              void* d_out, int out_size, void* d_ws, size_t ws_size,
                              hipStream_t stream){
  const float* x   = (const float*)d_in[0];
  const int*   ei  = (const int*)d_in[1];
  const int*   bat = (const int*)d_in[2];
  const float* W0  = (const float*)d_in[3];
  const float* b0  = (const float*)d_in[4];
  const float* W1  = (const float*)d_in[5];
  const float* b1  = (const float*)d_in[6];
  const float* W2  = (const float*)d_in[7];
  const float* b2  = (const float*)d_in[8];
  const float* Wf  = (const float*)d_in[9];
  const float* bf  = (const float*)d_in[10];
  int N = in_sizes[0] / D;
  int E = in_sizes[1] / 2;
  const int* srcp = ei;
  const int* dstp = ei + E;
  int nbk   = (N + BKNODES - 1) / BKNODES;
  int npart = (E + PCH - 1) / PCH;

  char* p = (char*)d_ws;
  auto alloc = [&](size_t bytes)->char*{
    char* r = p; p += (bytes + 255) & ~(size_t)255; return r;
  };
  float*    dinv    = (float*)alloc((size_t)N * 4);
  int*      row_ptr = (int*)alloc((size_t)(N + 1) * 4);
  int*      col     = (int*)alloc((size_t)E * 4);
  uint2*    epart   = (uint2*)alloc((size_t)E * 8);
  __half*   tmp     = (__half*)alloc((size_t)N * D * 2);
  float*    hbuf    = (float*)alloc((size_t)N * D * 4);
  unsigned* pk      = (unsigned*)alloc((size_t)NGRAPHS * D * 4);
  int*      bcnt    = (int*)alloc((size_t)MAXBK * 4);
  int*      bOff    = (int*)alloc((size_t)(MAXBK + 1) * 4);
  int*      bCur    = (int*)alloc((size_t)MAXBK * 4);

  hipMemsetAsync(bcnt, 0, (size_t)MAXBK * 4, stream);
  hipMemsetAsync(pk, 0, (size_t)NGRAPHS * D * 4, stream);

  k_bhist<<<npart, 256, 0, stream>>>(dstp, bcnt, E);
  k_bscan<<<1, 256, 0, stream>>>(bcnt, bOff, bCur, row_ptr, nbk, N, E);
  k_part<<<npart, 256, 0, stream>>>(srcp, dstp, bCur, epart, E);
  k_bfill<<<nbk, 256, 0, stream>>>(epart, bOff, row_ptr, col, dinv, N);

  int gblocks = (N + 63) / 64;
  // layer 0
  gemm128<<<gblocks, 256, 0, stream>>>(x, W0, tmp, N);
  k_agg<<<N, 128, 0, stream>>>(tmp, row_ptr, col, dinv, b0, hbuf, 1);
  // layer 1
  gemm128<<<gblocks, 256, 0, stream>>>(hbuf, W1, tmp, N);
  k_agg<<<N, 128, 0, stream>>>(tmp, row_ptr, col, dinv, b1, hbuf, 1);
  // layer 2 (no relu)
  gemm128<<<gblocks, 256, 0, stream>>>(hbuf, W2, tmp, N);
  k_agg<<<N, 128, 0, stream>>>(tmp, row_ptr, col, dinv, b2, hbuf, 0);
  // pool + classifier
  k_pool<<<(N + 127) / 128, 128, 0, stream>>>(hbuf, bat, pk, N);
  k_final<<<1, 128, 0, stream>>>(pk, Wf, bf, (float*)d_out);
}

// Round 6
// 546.129 us; speedup vs baseline: 1.8738x; 1.1181x over previous
//
#include <hip/hip_runtime.h>
#include <hip/hip_bf16.h>
#include <hip/hip_fp16.h>
#include <float.h>

#define D 128
#define NGRAPHS 64
#define BKSHIFT 9
#define BKNODES 512     // nodes per bucket
#define MAXBK 256       // max buckets (N<=131072)
#define PCH 4096        // edges per partition block (256 thr x 16)

// ---- ordered-float encoding for atomicMax on unsigned ----
__device__ __forceinline__ unsigned fkey(float f){
  unsigned u = __float_as_uint(f);
  return (u & 0x80000000u) ? ~u : (u | 0x80000000u);
}
__device__ __forceinline__ float funkey(unsigned k){
  unsigned u = (k & 0x80000000u) ? (k ^ 0x80000000u) : ~k;
  return __uint_as_float(u);
}

// A) bucket histogram: bcnt[b] = #edges with dst in bucket b
__global__ __launch_bounds__(256) void k_bhist(const int* __restrict__ dst,
    int* __restrict__ bcnt, int E){
  __shared__ int h[MAXBK];
  int t = threadIdx.x;
  for (int i = t; i < MAXBK; i += 256) h[i] = 0;
  __syncthreads();
  int e0 = blockIdx.x * PCH;
  #pragma unroll
  for (int j = 0; j < PCH / 256; j++){
    int e = e0 + t + j * 256;
    if (e < E) atomicAdd(&h[dst[e] >> BKSHIFT], 1);
  }
  __syncthreads();
  for (int i = t; i < MAXBK; i += 256) if (h[i]) atomicAdd(&bcnt[i], h[i]);
}

// B) scan bucket counts -> bOff[nbk+1], bCur; also row_ptr[N]=E
__global__ __launch_bounds__(256) void k_bscan(const int* __restrict__ bcnt,
    int* __restrict__ bOff, int* __restrict__ bCur, int* __restrict__ row_ptr,
    int nbk, int N, int E){
  __shared__ int sh[256];
  int t = threadIdx.x;
  int v = (t < nbk) ? bcnt[t] : 0;
  sh[t] = v; __syncthreads();
  for (int off = 1; off < 256; off <<= 1){
    int x = (t >= off) ? sh[t - off] : 0;
    __syncthreads();
    sh[t] += x;
    __syncthreads();
  }
  if (t < nbk){ int ex = sh[t] - v; bOff[t] = ex; bCur[t] = ex; }
  if (t == 0){ bOff[nbk] = E; row_ptr[N] = E; }
}

// C) partition edges into bucket-grouped epart[] with LDS-staged coalesced writes
__global__ __launch_bounds__(256) void k_part(const int* __restrict__ src,
    const int* __restrict__ dst, int* __restrict__ bCur,
    uint2* __restrict__ epart, int E){
  __shared__ int scnt[MAXBK], soff[MAXBK], sbase[MAXBK], scur[MAXBK];
  __shared__ int stmp[256];
  __shared__ uint2 stage[PCH];   // 32 KB
  int t = threadIdx.x;
  int e0 = blockIdx.x * PCH;
  int eN = E - e0; if (eN > PCH) eN = PCH;
  for (int i = t; i < MAXBK; i += 256){ scnt[i] = 0; scur[i] = 0; }
  __syncthreads();
  uint2 mye[PCH / 256];
  #pragma unroll
  for (int j = 0; j < PCH / 256; j++){
    int e = e0 + t + j * 256;
    if (e < E){
      mye[j].x = (unsigned)src[e];
      mye[j].y = (unsigned)dst[e];
      atomicAdd(&scnt[mye[j].y >> BKSHIFT], 1);
    }
  }
  __syncthreads();
  // exclusive scan of scnt (256 == MAXBK lanes)
  int v = scnt[t];
  stmp[t] = v; __syncthreads();
  for (int off = 1; off < 256; off <<= 1){
    int x = (t >= off) ? stmp[t - off] : 0;
    __syncthreads();
    stmp[t] += x;
    __syncthreads();
  }
  soff[t] = stmp[t] - v;
  // reserve this block's run in each bucket
  if (v > 0) sbase[t] = atomicAdd(&bCur[t], v);
  __syncthreads();
  // place edges into stage, grouped by bucket
  #pragma unroll
  for (int j = 0; j < PCH / 256; j++){
    int e = e0 + t + j * 256;
    if (e < E){
      int b = mye[j].y >> BKSHIFT;
      int l = atomicAdd(&scur[b], 1);
      stage[soff[b] + l] = mye[j];
    }
  }
  __syncthreads();
  // write out: consecutive threads -> consecutive slots within per-bucket runs
  for (int j = t; j < eN; j += 256){
    uint2 ed = stage[j];
    int b = (int)(ed.y >> BKSHIFT);
    epart[(size_t)sbase[b] + (j - soff[b])] = ed;
  }
}

// D) per-bucket CSR build: row_ptr, col, dinv — all state in LDS, confined writes
__global__ __launch_bounds__(256) void k_bfill(const uint2* __restrict__ epart,
    const int* __restrict__ bOff, int* __restrict__ row_ptr,
    int* __restrict__ col, float* __restrict__ dinv, int N){
  __shared__ int hc[BKNODES], off[BKNODES], cur[BKNODES];
  __shared__ int stmp[256];
  int b = blockIdx.x, t = threadIdx.x;
  int base = bOff[b], cntE = bOff[b + 1] - base;
  int node0 = b << BKSHIFT;
  int nloc = N - node0; if (nloc > BKNODES) nloc = BKNODES;
  for (int i = t; i < BKNODES; i += 256) hc[i] = 0;
  __syncthreads();
  for (int j = t; j < cntE; j += 256){
    uint2 ed = epart[(size_t)base + j];
    atomicAdd(&hc[ed.y - node0], 1);
  }
  __syncthreads();
  // exclusive scan of 512 via pairs on 256 threads
  int a0 = hc[2 * t], a1 = hc[2 * t + 1];
  int s = a0 + a1;
  stmp[t] = s; __syncthreads();
  for (int o = 1; o < 256; o <<= 1){
    int x = (t >= o) ? stmp[t - o] : 0;
    __syncthreads();
    stmp[t] += x;
    __syncthreads();
  }
  int ex = stmp[t] - s;
  off[2 * t] = ex; off[2 * t + 1] = ex + a0;
  __syncthreads();
  for (int i = t; i < nloc; i += 256){
    row_ptr[node0 + i] = base + off[i];
    dinv[node0 + i]    = rsqrtf((float)hc[i] + 1.0f);
    cur[i] = off[i];
  }
  __syncthreads();
  for (int j = t; j < cntE; j += 256){
    uint2 ed = epart[(size_t)base + j];
    int p = atomicAdd(&cur[ed.y - node0], 1);
    col[base + p] = (int)ed.x;
  }
}

// 5) fp32 GEMM: C[M,128] = A[M,128] @ W[128,128], output packed fp16.
__global__ __launch_bounds__(256) void gemm128(const float* __restrict__ A,
    const float* __restrict__ W, __half* __restrict__ C, int M){
  __shared__ float Ws[32 * 128];
  __shared__ float At[32 * 64];
  int t = threadIdx.x;
  int rowBase = blockIdx.x * 64;
  int c0 = (t & 31) * 4;
  int r0 = (t >> 5) * 8;
  float acc[8][4] = {};
  for (int k0 = 0; k0 < 128; k0 += 32){
    const float* wt = W + k0 * 128;
    #pragma unroll
    for (int j = 0; j < 4; j++){
      int idx = j * 1024 + t * 4;
      *(float4*)&Ws[idx] = *(const float4*)&wt[idx];
    }
    #pragma unroll
    for (int j = 0; j < 2; j++){
      int lid = t + j * 256;
      int row = lid >> 3;
      int kk  = (lid & 7) * 4;
      int gr = rowBase + row; if (gr >= M) gr = M - 1;
      float4 v = *(const float4*)&A[(size_t)gr * D + k0 + kk];
      At[(kk + 0) * 64 + row] = v.x;
      At[(kk + 1) * 64 + row] = v.y;
      At[(kk + 2) * 64 + row] = v.z;
      At[(kk + 3) * 64 + row] = v.w;
    }
    __syncthreads();
    #pragma unroll
    for (int kk = 0; kk < 32; kk++){
      float4 b = *(float4*)&Ws[kk * 128 + c0];
      float4 a0 = *(float4*)&At[kk * 64 + r0];
      float4 a1 = *(float4*)&At[kk * 64 + r0 + 4];
      float av[8] = {a0.x, a0.y, a0.z, a0.w, a1.x, a1.y, a1.z, a1.w};
      #pragma unroll
      for (int r = 0; r < 8; r++){
        acc[r][0] += av[r] * b.x;
        acc[r][1] += av[r] * b.y;
        acc[r][2] += av[r] * b.z;
        acc[r][3] += av[r] * b.w;
      }
    }
    __syncthreads();
  }
  #pragma unroll
  for (int r = 0; r < 8; r++){
    int gr = rowBase + r0 + r;
    if (gr < M){
      __half2 p0 = __floats2half2_rn(acc[r][0], acc[r][1]);
      __half2 p1 = __floats2half2_rn(acc[r][2], acc[r][3]);
      uint2 u;
      u.x = *(unsigned*)&p0;
      u.y = *(unsigned*)&p1;
      *(uint2*)&C[(size_t)gr * D + c0] = u;
    }
  }
}

// accumulate 8 halves (uint4) * w into acc[8]
__device__ __forceinline__ void acc8(float* acc, uint4 u, float w){
  __half2 h0 = *(__half2*)&u.x;
  __half2 h1 = *(__half2*)&u.y;
  __half2 h2 = *(__half2*)&u.z;
  __half2 h3 = *(__half2*)&u.w;
  float2 f0 = __half22float2(h0);
  float2 f1 = __half22float2(h1);
  float2 f2 = __half22float2(h2);
  float2 f3 = __half22float2(h3);
  acc[0] += f0.x * w; acc[1] += f0.y * w;
  acc[2] += f1.x * w; acc[3] += f1.y * w;
  acc[4] += f2.x * w; acc[5] += f2.y * w;
  acc[6] += f3.x * w; acc[7] += f3.y * w;
}

// 6) CSR aggregation v3: one wave per node, barrier-free, 2 gathers in flight/lane.
//    lane = way(0..3) x cg16(0..15); lane loads uint4 = 8 halves; 16 lanes = row.
//    Way-reduction via shfl_xor; lanes 0..15 do self+bias+relu epilogue.
__global__ __launch_bounds__(256) void k_agg(const __half* __restrict__ t,
    const int* __restrict__ row_ptr, const int* __restrict__ col,
    const float* __restrict__ dinv, const float* __restrict__ bias,
    float* __restrict__ out, int relu, int N){
  int node = blockIdx.x * 4 + (threadIdx.x >> 6);
  if (node >= N) return;
  int lane = threadIdx.x & 63;
  int way  = lane >> 4;          // 0..3
  int cg   = (lane & 15) * 8;    // first col of this lane's 8-half group
  float di = dinv[node];
  int beg = row_ptr[node], end = row_ptr[node + 1];
  float acc[8] = {0.f,0.f,0.f,0.f,0.f,0.f,0.f,0.f};
  int j = beg + way;
  // main loop: two independent gather chains in flight
  for (; j + 4 < end; j += 8){
    int s0 = col[j];
    int s1 = col[j + 4];
    float w0 = dinv[s0] * di;
    float w1 = dinv[s1] * di;
    uint4 u0 = *(const uint4*)&t[(size_t)s0 * D + cg];
    uint4 u1 = *(const uint4*)&t[(size_t)s1 * D + cg];
    acc8(acc, u0, w0);
    acc8(acc, u1, w1);
  }
  if (j < end){
    int s = col[j];
    float w = dinv[s] * di;
    uint4 u = *(const uint4*)&t[(size_t)s * D + cg];
    acc8(acc, u, w);
  }
  // reduce across the 4 ways (lanes 16, 32 apart)
  #pragma unroll
  for (int k = 0; k < 8; k++){
    acc[k] += __shfl_xor(acc[k], 16, 64);
    acc[k] += __shfl_xor(acc[k], 32, 64);
  }
  if (way == 0){
    uint4 su = *(const uint4*)&t[(size_t)node * D + cg];
    float dii = di * di;
    float self[8];
    {
      __half2 h0 = *(__half2*)&su.x; __half2 h1 = *(__half2*)&su.y;
      __half2 h2 = *(__half2*)&su.z; __half2 h3 = *(__half2*)&su.w;
      float2 f0 = __half22float2(h0); float2 f1 = __half22float2(h1);
      float2 f2 = __half22float2(h2); float2 f3 = __half22float2(h3);
      self[0]=f0.x; self[1]=f0.y; self[2]=f1.x; self[3]=f1.y;
      self[4]=f2.x; self[5]=f2.y; self[6]=f3.x; self[7]=f3.y;
    }
    float4 b0 = *(const float4*)&bias[cg];
    float4 b1 = *(const float4*)&bias[cg + 4];
    float o[8];
    o[0] = acc[0] + self[0] * dii + b0.x;
    o[1] = acc[1] + self[1] * dii + b0.y;
    o[2] = acc[2] + self[2] * dii + b0.z;
    o[3] = acc[3] + self[3] * dii + b0.w;
    o[4] = acc[4] + self[4] * dii + b1.x;
    o[5] = acc[5] + self[5] * dii + b1.y;
    o[6] = acc[6] + self[6] * dii + b1.z;
    o[7] = acc[7] + self[7] * dii + b1.w;
    if (relu){
      #pragma unroll
      for (int k = 0; k < 8; k++) o[k] = fmaxf(o[k], 0.f);
    }
    *(float4*)&out[(size_t)node * D + cg]     = *(float4*)&o[0];
    *(float4*)&out[(size_t)node * D + cg + 4] = *(float4*)&o[4];
  }
}

// 7) chunked segment-max into ordered-uint atomicMax (batch is sorted)
__global__ __launch_bounds__(128) void k_pool(const float* __restrict__ h,
    const int* __restrict__ batch, unsigned* __restrict__ pk, int N){
  int d = threadIdx.x;
  int n0 = blockIdx.x * 128;
  int nEnd = n0 + 128; if (nEnd > N) nEnd = N;
  float cur = -FLT_MAX;
  int curg = batch[n0];
  for (int n = n0; n < nEnd; n++){
    int g = batch[n];
    if (g != curg){
      atomicMax(&pk[curg * D + d], fkey(cur));
      cur = -FLT_MAX; curg = g;
    }
    cur = fmaxf(cur, h[(size_t)n * D + d]);
  }
  atomicMax(&pk[curg * D + d], fkey(cur));
}

// 8) final: out[64,2] = pooled @ Wf + bf
__global__ __launch_bounds__(128) void k_final(const unsigned* __restrict__ pk,
    const float* __restrict__ Wf, const float* __restrict__ bf,
    float* __restrict__ out){
  int t = threadIdx.x;
  int g = t >> 1, c = t & 1;
  float s = bf[c];
  for (int k = 0; k < D; k++)
    s += funkey(pk[g * D + k]) * Wf[k * 2 + c];
  out[g * 2 + c] = s;
}

extern "C" void kernel_launch(void* const* d_in, const int* in_sizes, int n_in,
                              void* d_out, int out_size, void* d_ws, size_t ws_size,
                              hipStream_t stream){
  const float* x   = (const float*)d_in[0];
  const int*   ei  = (const int*)d_in[1];
  const int*   bat = (const int*)d_in[2];
  const float* W0  = (const float*)d_in[3];
  const float* b0  = (const float*)d_in[4];
  const float* W1  = (const float*)d_in[5];
  const float* b1  = (const float*)d_in[6];
  const float* W2  = (const float*)d_in[7];
  const float* b2  = (const float*)d_in[8];
  const float* Wf  = (const float*)d_in[9];
  const float* bf  = (const float*)d_in[10];
  int N = in_sizes[0] / D;
  int E = in_sizes[1] / 2;
  const int* srcp = ei;
  const int* dstp = ei + E;
  int nbk   = (N + BKNODES - 1) / BKNODES;
  int npart = (E + PCH - 1) / PCH;

  char* p = (char*)d_ws;
  auto alloc = [&](size_t bytes)->char*{
    char* r = p; p += (bytes + 255) & ~(size_t)255; return r;
  };
  float*    dinv    = (float*)alloc((size_t)N * 4);
  int*      row_ptr = (int*)alloc((size_t)(N + 1) * 4);
  int*      col     = (int*)alloc((size_t)E * 4);
  uint2*    epart   = (uint2*)alloc((size_t)E * 8);
  __half*   tmp     = (__half*)alloc((size_t)N * D * 2);
  float*    hbuf    = (float*)alloc((size_t)N * D * 4);
  unsigned* pk      = (unsigned*)alloc((size_t)NGRAPHS * D * 4);
  int*      bcnt    = (int*)alloc((size_t)MAXBK * 4);
  int*      bOff    = (int*)alloc((size_t)(MAXBK + 1) * 4);
  int*      bCur    = (int*)alloc((size_t)MAXBK * 4);

  hipMemsetAsync(bcnt, 0, (size_t)MAXBK * 4, stream);
  hipMemsetAsync(pk, 0, (size_t)NGRAPHS * D * 4, stream);

  k_bhist<<<npart, 256, 0, stream>>>(dstp, bcnt, E);
  k_bscan<<<1, 256, 0, stream>>>(bcnt, bOff, bCur, row_ptr, nbk, N, E);
  k_part<<<npart, 256, 0, stream>>>(srcp, dstp, bCur, epart, E);
  k_bfill<<<nbk, 256, 0, stream>>>(epart, bOff, row_ptr, col, dinv, N);

  int gblocks = (N + 63) / 64;
  int ablocks = (N + 3) / 4;
  // layer 0
  gemm128<<<gblocks, 256, 0, stream>>>(x, W0, tmp, N);
  k_agg<<<ablocks, 256, 0, stream>>>(tmp, row_ptr, col, dinv, b0, hbuf, 1, N);
  // layer 1
  gemm128<<<gblocks, 256, 0, stream>>>(hbuf, W1, tmp, N);
  k_agg<<<ablocks, 256, 0, stream>>>(tmp, row_ptr, col, dinv, b1, hbuf, 1, N);
  // layer 2 (no relu)
  gemm128<<<gblocks, 256, 0, stream>>>(hbuf, W2, tmp, N);
  k_agg<<<ablocks, 256, 0, stream>>>(tmp, row_ptr, col, dinv, b2, hbuf, 0, N);
  // pool + classifier
  k_pool<<<(N + 127) / 128, 128, 0, stream>>>(hbuf, bat, pk, N);
  k_final<<<1, 128, 0, stream>>>(pk, Wf, bf, (float*)d_out);
}